// Round 1
// baseline (2198.735 us; speedup 1.0000x reference)
//
#include <hip/hip_runtime.h>

// ---------------------------------------------------------------------------
// RingLlamaAttention on MI355X (gfx950)
// Pipeline: cast f32->bf16 | rope tables | QKV gemms (bf16 MFMA) | rope apply
//           | flash attention (bf16 MFMA, fp32 softmax) | O gemm -> f32 out
// Shapes: B=2, S=4096, s_local=1024, H=4096, nh=32, hd=128, K=4096
// ---------------------------------------------------------------------------

using bf16x8 = __attribute__((ext_vector_type(8))) short;
using f32x4  = __attribute__((ext_vector_type(4))) float;

__device__ inline unsigned short f32_to_bf16_bits(float f) {
  unsigned int u = __float_as_uint(f);
  u += 0x7FFFu + ((u >> 16) & 1u);   // round-to-nearest-even
  return (unsigned short)(u >> 16);
}
__device__ inline float bf16_bits_to_f32(unsigned short h) {
  return __uint_as_float(((unsigned int)h) << 16);
}

// ---- elementwise f32 -> bf16 cast (float4 / ushort4 vectorized) ----
__global__ void cast_f32_bf16(const float* __restrict__ in,
                              unsigned short* __restrict__ out, long n4) {
  long i = (long)blockIdx.x * blockDim.x + threadIdx.x;
  long stride = (long)gridDim.x * blockDim.x;
  for (; i < n4; i += stride) {
    float4 v = reinterpret_cast<const float4*>(in)[i];
    ushort4 o;
    o.x = f32_to_bf16_bits(v.x);
    o.y = f32_to_bf16_bits(v.y);
    o.z = f32_to_bf16_bits(v.z);
    o.w = f32_to_bf16_bits(v.w);
    reinterpret_cast<ushort4*>(out)[i] = o;
  }
}

// ---- RoPE cos/sin tables: pos 0..4095 x freq 0..63, fp32 ----
__global__ void rope_tables(float* __restrict__ cos_t, float* __restrict__ sin_t) {
  int idx = blockIdx.x * 256 + threadIdx.x;
  if (idx >= 4096 * 64) return;
  int p = idx >> 6, i = idx & 63;
  // inv_freq = theta^(-i/64), theta=10000 ; ln(10000)=9.210340371976184
  float inv = __expf(-(float)i * (9.210340371976184f / 64.0f));
  float f = (float)p * inv;
  cos_t[idx] = cosf(f);
  sin_t[idx] = sinf(f);
}

// ---- RoPE apply in-place on bf16 buffer [tok][32*128], pos = tok & pos_mask ----
__global__ void rope_apply(unsigned short* __restrict__ buf,
                           const float* __restrict__ cos_t,
                           const float* __restrict__ sin_t,
                           long total, int pos_mask) {
  long idx = (long)blockIdx.x * 256 + threadIdx.x;
  if (idx >= total) return;
  long tok = idx >> 11;            // 2048 (head,freq) pairs per token
  int rem  = (int)(idx & 2047);
  int head = rem >> 6, i = rem & 63;
  int pos  = (int)(tok & (long)pos_mask);
  float c = cos_t[pos * 64 + i], s = sin_t[pos * 64 + i];
  long base = tok * 4096 + head * 128 + i;
  float x1 = bf16_bits_to_f32(buf[base]);
  float x2 = bf16_bits_to_f32(buf[base + 64]);
  buf[base]      = f32_to_bf16_bits(x1 * c - x2 * s);
  buf[base + 64] = f32_to_bf16_bits(x2 * c + x1 * s);
}

// ---- GEMM C[M,N] = A[M,K] * B[N,K]^T, K=4096, bf16 in, f32 acc ----
// 128x128 tile, 4 waves (2x2 of 64x64), BK=32, single-buffered LDS (m97-family)
__device__ inline void storeC(float* p, float v) { *p = v; }
__device__ inline void storeC(unsigned short* p, float v) { *p = f32_to_bf16_bits(v); }

template <typename OUT_T>
__global__ __launch_bounds__(256) void gemm_bt(const unsigned short* __restrict__ A,
                                               const unsigned short* __restrict__ B,
                                               OUT_T* __restrict__ C,
                                               long Astride_z, long Cstride_z, int N) {
  __shared__ unsigned short As[128 * 32];
  __shared__ unsigned short Bs[128 * 32];
  const int tid = threadIdx.x;
  const int bn = blockIdx.x, bm = blockIdx.y, bz = blockIdx.z;
  const unsigned short* Ab = A + (long)bz * Astride_z + (long)bm * 128 * 4096;
  const unsigned short* Bb = B + (long)bn * 128 * 4096;
  OUT_T* Cb = C + (long)bz * Cstride_z + (long)bm * 128 * N + (long)bn * 128;

  const int lane = tid & 63;
  const int w = tid >> 6;
  const int wr = (w >> 1) * 64, wc = (w & 1) * 64;
  const int fr = lane & 15, fg = lane >> 4;

  f32x4 acc[4][4] = {};

  const int c0 = tid, c1 = tid + 256;
  const int rA0 = c0 >> 2, kc0 = c0 & 3;
  const int rA1 = c1 >> 2, kc1 = c1 & 3;

  for (int k0 = 0; k0 < 4096; k0 += 32) {
    bf16x8 va0 = *reinterpret_cast<const bf16x8*>(Ab + (long)rA0 * 4096 + k0 + kc0 * 8);
    bf16x8 va1 = *reinterpret_cast<const bf16x8*>(Ab + (long)rA1 * 4096 + k0 + kc1 * 8);
    bf16x8 vb0 = *reinterpret_cast<const bf16x8*>(Bb + (long)rA0 * 4096 + k0 + kc0 * 8);
    bf16x8 vb1 = *reinterpret_cast<const bf16x8*>(Bb + (long)rA1 * 4096 + k0 + kc1 * 8);
    *reinterpret_cast<bf16x8*>(As + c0 * 8) = va0;
    *reinterpret_cast<bf16x8*>(As + c1 * 8) = va1;
    *reinterpret_cast<bf16x8*>(Bs + c0 * 8) = vb0;
    *reinterpret_cast<bf16x8*>(Bs + c1 * 8) = vb1;
    __syncthreads();
    bf16x8 af[4], bfv[4];
#pragma unroll
    for (int m = 0; m < 4; m++)
      af[m] = *reinterpret_cast<const bf16x8*>(As + (wr + m * 16 + fr) * 32 + fg * 8);
#pragma unroll
    for (int n = 0; n < 4; n++)
      bfv[n] = *reinterpret_cast<const bf16x8*>(Bs + (wc + n * 16 + fr) * 32 + fg * 8);
#pragma unroll
    for (int m = 0; m < 4; m++)
#pragma unroll
      for (int n = 0; n < 4; n++)
        acc[m][n] = __builtin_amdgcn_mfma_f32_16x16x32_bf16(af[m], bfv[n], acc[m][n], 0, 0, 0);
    __syncthreads();
  }
  // epilogue: D col = lane&15, row = (lane>>4)*4 + reg  [m89-verified]
#pragma unroll
  for (int m = 0; m < 4; m++)
#pragma unroll
    for (int n = 0; n < 4; n++)
#pragma unroll
      for (int r = 0; r < 4; r++) {
        int row = wr + m * 16 + fg * 4 + r;
        int col = wc + n * 16 + fr;
        storeC(Cb + (long)row * N + col, acc[m][n][r]);
      }
}

// ---- flash attention: grid (16 qtiles, 32 heads, 2 batch), 4 waves ----
// Each block: 64 q rows (16 per wave); loop kv tiles of 64 keys.
__global__ __launch_bounds__(256) void attn_fwd(const unsigned short* __restrict__ qb,
                                                const unsigned short* __restrict__ kb,
                                                const unsigned short* __restrict__ vb,
                                                unsigned short* __restrict__ ob) {
  __shared__ unsigned short Ks[64 * 136];   // [key][d] padded to 136
  __shared__ unsigned short Vt[128 * 72];   // [d][key] padded to 72 (transposed)
  __shared__ unsigned short Ps[4][16 * 72]; // per-wave P [q][key] padded to 72

  const int qt = blockIdx.x, h = blockIdx.y, b = blockIdx.z;
  const int tid = threadIdx.x, w = tid >> 6, lane = tid & 63;
  const int fr = lane & 15, fg = lane >> 4;

  // Q fragments (A-operand): row = fr, k = fg*8 + c*32  (held in regs for whole block)
  bf16x8 qf[4];
  {
    const unsigned short* qptr =
        qb + ((long)b * 1024 + qt * 64 + w * 16 + fr) * 4096 + h * 128 + fg * 8;
#pragma unroll
    for (int c = 0; c < 4; c++) qf[c] = *reinterpret_cast<const bf16x8*>(qptr + c * 32);
  }

  f32x4 outa[8] = {};            // O accumulator: rows fg*4+r, col fr+16*ds
  float m_run[4], l_run[4];
#pragma unroll
  for (int r = 0; r < 4; r++) { m_run[r] = -1e30f; l_run[r] = 0.0f; }
  const float scale = 0.088388347648318447f;  // 1/sqrt(128)

  for (int kv0 = 0; kv0 < 4096; kv0 += 64) {
    __syncthreads();  // protect previous tile's LDS reads
    // stage K tile [64][128] row-major (padded)
#pragma unroll
    for (int i = 0; i < 4; i++) {
      int c = tid + 256 * i;
      int key = c >> 4, dc = c & 15;
      const unsigned short* g = kb + ((long)b * 4096 + kv0 + key) * 4096 + h * 128 + dc * 8;
      *reinterpret_cast<bf16x8*>(&Ks[key * 136 + dc * 8]) = *reinterpret_cast<const bf16x8*>(g);
    }
    // stage V transposed -> Vt[d][key]
#pragma unroll
    for (int i = 0; i < 4; i++) {
      int c = tid + 256 * i;
      int key = c >> 4, dc = c & 15;
      const unsigned short* g = vb + ((long)b * 4096 + kv0 + key) * 4096 + h * 128 + dc * 8;
      bf16x8 v = *reinterpret_cast<const bf16x8*>(g);
#pragma unroll
      for (int j = 0; j < 8; j++) Vt[(dc * 8 + j) * 72 + key] = ((unsigned short*)&v)[j];
    }
    __syncthreads();

    // S = Q K^T : 4 key-subtiles of 16, K-dim 128 = 4 x 32
    f32x4 sacc[4];
#pragma unroll
    for (int ks = 0; ks < 4; ks++) {
      f32x4 a = {0.f, 0.f, 0.f, 0.f};
#pragma unroll
      for (int c = 0; c < 4; c++) {
        bf16x8 kf = *reinterpret_cast<const bf16x8*>(&Ks[(ks * 16 + fr) * 136 + c * 32 + fg * 8]);
        a = __builtin_amdgcn_mfma_f32_16x16x32_bf16(qf[c], kf, a, 0, 0, 0);
      }
      sacc[ks] = a;
    }

    // online softmax per q-row (row = fg*4+r; 16 lanes of same fg share a row)
    float p[4][4];
#pragma unroll
    for (int r = 0; r < 4; r++) {
      float mx = fmaxf(fmaxf(sacc[0][r], sacc[1][r]), fmaxf(sacc[2][r], sacc[3][r])) * scale;
      mx = fmaxf(mx, __shfl_xor(mx, 1));
      mx = fmaxf(mx, __shfl_xor(mx, 2));
      mx = fmaxf(mx, __shfl_xor(mx, 4));
      mx = fmaxf(mx, __shfl_xor(mx, 8));
      float mnew = fmaxf(m_run[r], mx);
      float sum = 0.f;
#pragma unroll
      for (int ks = 0; ks < 4; ks++) {
        float pv = __expf(sacc[ks][r] * scale - mnew);
        p[ks][r] = pv;
        sum += pv;
      }
      sum += __shfl_xor(sum, 1);
      sum += __shfl_xor(sum, 2);
      sum += __shfl_xor(sum, 4);
      sum += __shfl_xor(sum, 8);
      float ef = __expf(m_run[r] - mnew);
      l_run[r] = l_run[r] * ef + sum;
      m_run[r] = mnew;
#pragma unroll
      for (int ds = 0; ds < 8; ds++) outa[ds][r] *= ef;
    }

    // P -> LDS (wave-private), layout [q][key] for A-operand reads
#pragma unroll
    for (int r = 0; r < 4; r++)
#pragma unroll
      for (int ks = 0; ks < 4; ks++)
        Ps[w][(fg * 4 + r) * 72 + ks * 16 + fr] = f32_to_bf16_bits(p[ks][r]);

    // O += P V : A = P[q=fr][k=key], B^T = Vt[d=fr-col][k=key]
#pragma unroll
    for (int c2 = 0; c2 < 2; c2++) {
      bf16x8 pf = *reinterpret_cast<const bf16x8*>(&Ps[w][fr * 72 + c2 * 32 + fg * 8]);
#pragma unroll
      for (int ds = 0; ds < 8; ds++) {
        bf16x8 vf = *reinterpret_cast<const bf16x8*>(&Vt[(ds * 16 + fr) * 72 + c2 * 32 + fg * 8]);
        outa[ds] = __builtin_amdgcn_mfma_f32_16x16x32_bf16(pf, vf, outa[ds], 0, 0, 0);
      }
    }
  }

  // normalize + store bf16 [tok][h*128+d]
#pragma unroll
  for (int r = 0; r < 4; r++) {
    float inv = 1.0f / l_run[r];
    unsigned short* op =
        ob + ((long)b * 1024 + qt * 64 + w * 16 + fg * 4 + r) * 4096 + h * 128;
#pragma unroll
    for (int ds = 0; ds < 8; ds++) op[ds * 16 + fr] = f32_to_bf16_bits(outa[ds][r] * inv);
  }
}

// ---------------------------------------------------------------------------
extern "C" void kernel_launch(void* const* d_in, const int* in_sizes, int n_in,
                              void* d_out, int out_size, void* d_ws, size_t ws_size,
                              hipStream_t stream) {
  const float* hs = (const float*)d_in[0];
  const float* wq = (const float*)d_in[1];
  const float* wk = (const float*)d_in[2];
  const float* wv = (const float*)d_in[3];
  const float* wo = (const float*)d_in[4];
  float* out = (float*)d_out;

  const long hsN = 2L * 4096 * 4096;  // 33.5M elems
  const long wN  = 4096L * 4096;      // 16.8M elems

  unsigned short* hs_b = (unsigned short*)d_ws;
  unsigned short* wq_b = hs_b + hsN;
  unsigned short* wk_b = wq_b + wN;
  unsigned short* wv_b = wk_b + wN;
  unsigned short* wo_b = wv_b + wN;
  unsigned short* q_b  = wo_b + wN;             // 2048 x 4096
  unsigned short* k_b  = q_b + 2048L * 4096;    // 8192 x 4096
  unsigned short* v_b  = k_b + 8192L * 4096;    // 8192 x 4096
  unsigned short* at_b = v_b + 8192L * 4096;    // 2048 x 4096
  float* cos_t = (float*)(at_b + 2048L * 4096);
  float* sin_t = cos_t + 4096 * 64;

  // casts f32 -> bf16
  cast_f32_bf16<<<dim3(4096), dim3(256), 0, stream>>>(hs, hs_b, hsN / 4);
  cast_f32_bf16<<<dim3(2048), dim3(256), 0, stream>>>(wq, wq_b, wN / 4);
  cast_f32_bf16<<<dim3(2048), dim3(256), 0, stream>>>(wk, wk_b, wN / 4);
  cast_f32_bf16<<<dim3(2048), dim3(256), 0, stream>>>(wv, wv_b, wN / 4);
  cast_f32_bf16<<<dim3(2048), dim3(256), 0, stream>>>(wo, wo_b, wN / 4);

  rope_tables<<<dim3(1024), dim3(256), 0, stream>>>(cos_t, sin_t);

  // Q: M=1024 per batch (first 1024 rows of each batch), K: M=4096, V: M=4096
  gemm_bt<unsigned short><<<dim3(32, 8, 2), dim3(256), 0, stream>>>(
      hs_b, wq_b, q_b, 4096L * 4096, 1024L * 4096, 4096);
  gemm_bt<unsigned short><<<dim3(32, 32, 2), dim3(256), 0, stream>>>(
      hs_b, wk_b, k_b, 4096L * 4096, 4096L * 4096, 4096);
  gemm_bt<unsigned short><<<dim3(32, 32, 2), dim3(256), 0, stream>>>(
      hs_b, wv_b, v_b, 4096L * 4096, 4096L * 4096, 4096);

  // RoPE (q: pos = tok % 1024, k: pos = tok % 4096)
  rope_apply<<<dim3(16384), dim3(256), 0, stream>>>(q_b, cos_t, sin_t, 2048L * 2048, 1023);
  rope_apply<<<dim3(65536), dim3(256), 0, stream>>>(k_b, cos_t, sin_t, 8192L * 2048, 4095);

  // attention
  attn_fwd<<<dim3(16, 32, 2), dim3(256), 0, stream>>>(q_b, k_b, v_b, at_b);

  // output projection -> f32 d_out
  gemm_bt<float><<<dim3(32, 16, 1), dim3(256), 0, stream>>>(
      at_b, wo_b, out, 0L, 0L, 4096);
}

// Round 2
// 1362.856 us; speedup vs baseline: 1.6133x; 1.6133x over previous
//
#include <hip/hip_runtime.h>

// ---------------------------------------------------------------------------
// RingLlamaAttention on MI355X (gfx950)
// Pipeline: cast f32->bf16 | rope tables | QKV gemms (bf16 MFMA, global_load_lds)
//           | rope apply | flash attention (bf16 MFMA, swizzled V^T LDS,
//             reg-prefetched K/V staging) | O gemm -> f32 out
// Shapes: B=2, S=4096, s_local=1024, H=4096, nh=32, hd=128, K=4096
// ---------------------------------------------------------------------------

using bf16x8 = __attribute__((ext_vector_type(8))) short;
using f32x4  = __attribute__((ext_vector_type(4))) float;

__device__ inline unsigned short f32_to_bf16_bits(float f) {
  unsigned int u = __float_as_uint(f);
  u += 0x7FFFu + ((u >> 16) & 1u);   // round-to-nearest-even
  return (unsigned short)(u >> 16);
}
__device__ inline float bf16_bits_to_f32(unsigned short h) {
  return __uint_as_float(((unsigned int)h) << 16);
}

// async global->LDS, 16B per lane (m97 pattern; dest must be wave-uniform + lane*16)
__device__ __forceinline__ void load_lds16(const unsigned short* g, unsigned short* l) {
  __builtin_amdgcn_global_load_lds(
      (const __attribute__((address_space(1))) void*)g,
      (__attribute__((address_space(3))) void*)l, 16, 0, 0);
}

// ---- elementwise f32 -> bf16 cast (float4 / ushort4 vectorized) ----
__global__ void cast_f32_bf16(const float* __restrict__ in,
                              unsigned short* __restrict__ out, long n4) {
  long i = (long)blockIdx.x * blockDim.x + threadIdx.x;
  long stride = (long)gridDim.x * blockDim.x;
  for (; i < n4; i += stride) {
    float4 v = reinterpret_cast<const float4*>(in)[i];
    ushort4 o;
    o.x = f32_to_bf16_bits(v.x);
    o.y = f32_to_bf16_bits(v.y);
    o.z = f32_to_bf16_bits(v.z);
    o.w = f32_to_bf16_bits(v.w);
    reinterpret_cast<ushort4*>(out)[i] = o;
  }
}

// ---- RoPE cos/sin tables: pos 0..4095 x freq 0..63, fp32 ----
__global__ void rope_tables(float* __restrict__ cos_t, float* __restrict__ sin_t) {
  int idx = blockIdx.x * 256 + threadIdx.x;
  if (idx >= 4096 * 64) return;
  int p = idx >> 6, i = idx & 63;
  float inv = __expf(-(float)i * (9.210340371976184f / 64.0f));  // theta^(-i/64)
  float f = (float)p * inv;
  cos_t[idx] = cosf(f);
  sin_t[idx] = sinf(f);
}

// ---- RoPE apply in-place on bf16 buffer [tok][32*128], pos = tok & pos_mask ----
__global__ void rope_apply(unsigned short* __restrict__ buf,
                           const float* __restrict__ cos_t,
                           const float* __restrict__ sin_t,
                           long total, int pos_mask) {
  long idx = (long)blockIdx.x * 256 + threadIdx.x;
  if (idx >= total) return;
  long tok = idx >> 11;            // 2048 (head,freq) pairs per token
  int rem  = (int)(idx & 2047);
  int head = rem >> 6, i = rem & 63;
  int pos  = (int)(tok & (long)pos_mask);
  float c = cos_t[pos * 64 + i], s = sin_t[pos * 64 + i];
  long base = tok * 4096 + head * 128 + i;
  float x1 = bf16_bits_to_f32(buf[base]);
  float x2 = bf16_bits_to_f32(buf[base + 64]);
  buf[base]      = f32_to_bf16_bits(x1 * c - x2 * s);
  buf[base + 64] = f32_to_bf16_bits(x2 * c + x1 * s);
}

// ---- GEMM C[M,N] = A[M,K] * B[N,K]^T, K=4096, bf16 in, f32 acc ----
// 128x128 tile, 4 waves (2x2 of 64x64), BK=32, global_load_lds staging (m97)
__device__ inline void storeC(float* p, float v) { *p = v; }
__device__ inline void storeC(unsigned short* p, float v) { *p = f32_to_bf16_bits(v); }

template <typename OUT_T>
__global__ __launch_bounds__(256) void gemm_bt(const unsigned short* __restrict__ A,
                                               const unsigned short* __restrict__ B,
                                               OUT_T* __restrict__ C,
                                               long Astride_z, long Cstride_z, int N) {
  __shared__ unsigned short As[128 * 32];
  __shared__ unsigned short Bs[128 * 32];
  const int tid = threadIdx.x;
  const int bn = blockIdx.x, bm = blockIdx.y, bz = blockIdx.z;
  const unsigned short* Ab = A + (long)bz * Astride_z + (long)bm * 128 * 4096;
  const unsigned short* Bb = B + (long)bn * 128 * 4096;
  OUT_T* Cb = C + (long)bz * Cstride_z + (long)bm * 128 * N + (long)bn * 128;

  const int lane = tid & 63;
  const int w = tid >> 6;
  const int wr = (w >> 1) * 64, wc = (w & 1) * 64;
  const int fr = lane & 15, fg = lane >> 4;

  f32x4 acc[4][4] = {};

  const int c0 = tid, c1 = tid + 256;
  const int rA0 = c0 >> 2, kc0 = c0 & 3;
  const int rA1 = c1 >> 2, kc1 = c1 & 3;

  for (int k0 = 0; k0 < 4096; k0 += 32) {
    // async global->LDS staging (16B/lane, lane-linear LDS dest)
    load_lds16(Ab + (long)rA0 * 4096 + k0 + kc0 * 8, As + c0 * 8);
    load_lds16(Ab + (long)rA1 * 4096 + k0 + kc1 * 8, As + c1 * 8);
    load_lds16(Bb + (long)rA0 * 4096 + k0 + kc0 * 8, Bs + c0 * 8);
    load_lds16(Bb + (long)rA1 * 4096 + k0 + kc1 * 8, Bs + c1 * 8);
    __syncthreads();   // compiler drains vmcnt before barrier
    bf16x8 af[4], bfv[4];
#pragma unroll
    for (int m = 0; m < 4; m++)
      af[m] = *reinterpret_cast<const bf16x8*>(As + (wr + m * 16 + fr) * 32 + fg * 8);
#pragma unroll
    for (int n = 0; n < 4; n++)
      bfv[n] = *reinterpret_cast<const bf16x8*>(Bs + (wc + n * 16 + fr) * 32 + fg * 8);
#pragma unroll
    for (int m = 0; m < 4; m++)
#pragma unroll
      for (int n = 0; n < 4; n++)
        acc[m][n] = __builtin_amdgcn_mfma_f32_16x16x32_bf16(af[m], bfv[n], acc[m][n], 0, 0, 0);
    __syncthreads();
  }
  // epilogue: D col = lane&15, row = (lane>>4)*4 + reg  [m89-verified]
#pragma unroll
  for (int m = 0; m < 4; m++)
#pragma unroll
    for (int n = 0; n < 4; n++)
#pragma unroll
      for (int r = 0; r < 4; r++) {
        int row = wr + m * 16 + fg * 4 + r;
        int col = wc + n * 16 + fr;
        storeC(Cb + (long)row * N + col, acc[m][n][r]);
      }
}

// ---- flash attention: grid (16 qtiles, 32 heads, 2 batch), 4 waves ----
// 64 q rows/block (16 per wave); kv tiles of 64 keys; K/V reg-prefetched (T14);
// V^T staged with XOR chunk swizzle (conflict-free scalar transpose writes).
__global__ __launch_bounds__(256) void attn_fwd(const unsigned short* __restrict__ qb,
                                                const unsigned short* __restrict__ kb,
                                                const unsigned short* __restrict__ vb,
                                                unsigned short* __restrict__ ob) {
  __shared__ unsigned short Ks[64 * 136];   // [key][d], stride 136 (272B, 16B-mult)
  __shared__ unsigned short Vt[128 * 80];   // [d][keychunk swizzled], stride 80
  __shared__ unsigned short Ps[4][16 * 72]; // per-wave P [q][key]

  const int qt = blockIdx.x, h = blockIdx.y, b = blockIdx.z;
  const int tid = threadIdx.x, w = tid >> 6, lane = tid & 63;
  const int fr = lane & 15, fg = lane >> 4;

  const unsigned short* kbase = kb + (long)b * 4096 * 4096 + h * 128;
  const unsigned short* vbase = vb + (long)b * 4096 * 4096 + h * 128;

  // Q fragments (A-operand): row = fr, k = fg*8 + c*32  (regs for whole block)
  bf16x8 qf[4];
  {
    const unsigned short* qptr =
        qb + ((long)b * 1024 + qt * 64 + w * 16 + fr) * 4096 + h * 128 + fg * 8;
#pragma unroll
    for (int c = 0; c < 4; c++) qf[c] = *reinterpret_cast<const bf16x8*>(qptr + c * 32);
  }

  f32x4 outa[8] = {};            // O accumulator: rows fg*4+r, col fr+16*ds
  float m_run[4], l_run[4];
#pragma unroll
  for (int r = 0; r < 4; r++) { m_run[r] = -1e30f; l_run[r] = 0.0f; }
  const float scale = 0.088388347648318447f;  // 1/sqrt(128)

  // staging coords: c = tid + 256*i -> key = c>>4, dc = c&15
  // prefetch tile 0 into regs
  bf16x8 kreg[4], vreg[4];
#pragma unroll
  for (int i = 0; i < 4; i++) {
    int c = tid + 256 * i;
    int key = c >> 4, dc = c & 15;
    kreg[i] = *reinterpret_cast<const bf16x8*>(kbase + (long)key * 4096 + dc * 8);
    vreg[i] = *reinterpret_cast<const bf16x8*>(vbase + (long)key * 4096 + dc * 8);
  }

  for (int kv0 = 0; kv0 < 4096; kv0 += 64) {
    __syncthreads();  // previous tile's LDS reads done
    // write staged regs -> LDS
#pragma unroll
    for (int i = 0; i < 4; i++) {
      int c = tid + 256 * i;
      int key = c >> 4, dc = c & 15;
      *reinterpret_cast<bf16x8*>(&Ks[key * 136 + dc * 8]) = kreg[i];
      const unsigned short* vv = (const unsigned short*)&vreg[i];
      int chunkbase = ((key >> 3) ^ (dc & 7)) << 3;  // XOR swizzle: spreads dc over banks
      int keylo = key & 7;
#pragma unroll
      for (int j = 0; j < 8; j++)
        Vt[(dc * 8 + j) * 80 + chunkbase + keylo] = vv[j];
    }
    __syncthreads();
    // prefetch next tile (hides HBM latency under compute below)
    if (kv0 + 64 < 4096) {
#pragma unroll
      for (int i = 0; i < 4; i++) {
        int c = tid + 256 * i;
        int key = c >> 4, dc = c & 15;
        kreg[i] = *reinterpret_cast<const bf16x8*>(kbase + (long)(kv0 + 64 + key) * 4096 + dc * 8);
        vreg[i] = *reinterpret_cast<const bf16x8*>(vbase + (long)(kv0 + 64 + key) * 4096 + dc * 8);
      }
    }

    // S = Q K^T : 4 key-subtiles of 16, K-dim 128 = 4 x 32
    f32x4 sacc[4];
#pragma unroll
    for (int ks = 0; ks < 4; ks++) {
      f32x4 a = {0.f, 0.f, 0.f, 0.f};
#pragma unroll
      for (int c = 0; c < 4; c++) {
        bf16x8 kf = *reinterpret_cast<const bf16x8*>(&Ks[(ks * 16 + fr) * 136 + c * 32 + fg * 8]);
        a = __builtin_amdgcn_mfma_f32_16x16x32_bf16(qf[c], kf, a, 0, 0, 0);
      }
      sacc[ks] = a;
    }

    // online softmax per q-row (row = fg*4+r; 16 lanes of same fg share a row)
    float p[4][4];
#pragma unroll
    for (int r = 0; r < 4; r++) {
      float mx = fmaxf(fmaxf(sacc[0][r], sacc[1][r]), fmaxf(sacc[2][r], sacc[3][r])) * scale;
      mx = fmaxf(mx, __shfl_xor(mx, 1));
      mx = fmaxf(mx, __shfl_xor(mx, 2));
      mx = fmaxf(mx, __shfl_xor(mx, 4));
      mx = fmaxf(mx, __shfl_xor(mx, 8));
      float mnew = fmaxf(m_run[r], mx);
      float sum = 0.f;
#pragma unroll
      for (int ks = 0; ks < 4; ks++) {
        float pv = __expf(sacc[ks][r] * scale - mnew);
        p[ks][r] = pv;
        sum += pv;
      }
      sum += __shfl_xor(sum, 1);
      sum += __shfl_xor(sum, 2);
      sum += __shfl_xor(sum, 4);
      sum += __shfl_xor(sum, 8);
      float ef = __expf(m_run[r] - mnew);
      l_run[r] = l_run[r] * ef + sum;
      m_run[r] = mnew;
#pragma unroll
      for (int ds = 0; ds < 8; ds++) outa[ds][r] *= ef;
    }

    // P -> LDS (wave-private), layout [q][key] for A-operand reads
#pragma unroll
    for (int r = 0; r < 4; r++)
#pragma unroll
      for (int ks = 0; ks < 4; ks++)
        Ps[w][(fg * 4 + r) * 72 + ks * 16 + fr] = f32_to_bf16_bits(p[ks][r]);

    // O += P V : A = P[q=fr][k], B^T = Vt[d=row][k] (swizzled chunks)
#pragma unroll
    for (int c2 = 0; c2 < 2; c2++) {
      bf16x8 pf = *reinterpret_cast<const bf16x8*>(&Ps[w][fr * 72 + c2 * 32 + fg * 8]);
#pragma unroll
      for (int ds = 0; ds < 8; ds++) {
        int row = ds * 16 + fr;
        int chunk = (c2 * 4 + fg) ^ ((row >> 3) & 7);
        bf16x8 vf = *reinterpret_cast<const bf16x8*>(&Vt[row * 80 + chunk * 8]);
        outa[ds] = __builtin_amdgcn_mfma_f32_16x16x32_bf16(pf, vf, outa[ds], 0, 0, 0);
      }
    }
  }

  // normalize + store bf16 [tok][h*128+d]
#pragma unroll
  for (int r = 0; r < 4; r++) {
    float inv = 1.0f / l_run[r];
    unsigned short* op =
        ob + ((long)b * 1024 + qt * 64 + w * 16 + fg * 4 + r) * 4096 + h * 128;
#pragma unroll
    for (int ds = 0; ds < 8; ds++) op[ds * 16 + fr] = f32_to_bf16_bits(outa[ds][r] * inv);
  }
}

// ---------------------------------------------------------------------------
extern "C" void kernel_launch(void* const* d_in, const int* in_sizes, int n_in,
                              void* d_out, int out_size, void* d_ws, size_t ws_size,
                              hipStream_t stream) {
  const float* hs = (const float*)d_in[0];
  const float* wq = (const float*)d_in[1];
  const float* wk = (const float*)d_in[2];
  const float* wv = (const float*)d_in[3];
  const float* wo = (const float*)d_in[4];
  float* out = (float*)d_out;

  const long hsN = 2L * 4096 * 4096;
  const long wN  = 4096L * 4096;

  unsigned short* hs_b = (unsigned short*)d_ws;
  unsigned short* wq_b = hs_b + hsN;
  unsigned short* wk_b = wq_b + wN;
  unsigned short* wv_b = wk_b + wN;
  unsigned short* wo_b = wv_b + wN;
  unsigned short* q_b  = wo_b + wN;             // 2048 x 4096
  unsigned short* k_b  = q_b + 2048L * 4096;    // 8192 x 4096
  unsigned short* v_b  = k_b + 8192L * 4096;    // 8192 x 4096
  unsigned short* at_b = v_b + 8192L * 4096;    // 2048 x 4096
  float* cos_t = (float*)(at_b + 2048L * 4096);
  float* sin_t = cos_t + 4096 * 64;

  // casts f32 -> bf16
  cast_f32_bf16<<<dim3(4096), dim3(256), 0, stream>>>(hs, hs_b, hsN / 4);
  cast_f32_bf16<<<dim3(2048), dim3(256), 0, stream>>>(wq, wq_b, wN / 4);
  cast_f32_bf16<<<dim3(2048), dim3(256), 0, stream>>>(wk, wk_b, wN / 4);
  cast_f32_bf16<<<dim3(2048), dim3(256), 0, stream>>>(wv, wv_b, wN / 4);
  cast_f32_bf16<<<dim3(2048), dim3(256), 0, stream>>>(wo, wo_b, wN / 4);

  rope_tables<<<dim3(1024), dim3(256), 0, stream>>>(cos_t, sin_t);

  gemm_bt<unsigned short><<<dim3(32, 8, 2), dim3(256), 0, stream>>>(
      hs_b, wq_b, q_b, 4096L * 4096, 1024L * 4096, 4096);
  gemm_bt<unsigned short><<<dim3(32, 32, 2), dim3(256), 0, stream>>>(
      hs_b, wk_b, k_b, 4096L * 4096, 4096L * 4096, 4096);
  gemm_bt<unsigned short><<<dim3(32, 32, 2), dim3(256), 0, stream>>>(
      hs_b, wv_b, v_b, 4096L * 4096, 4096L * 4096, 4096);

  rope_apply<<<dim3(16384), dim3(256), 0, stream>>>(q_b, cos_t, sin_t, 2048L * 2048, 1023);
  rope_apply<<<dim3(65536), dim3(256), 0, stream>>>(k_b, cos_t, sin_t, 8192L * 2048, 4095);

  attn_fwd<<<dim3(16, 32, 2), dim3(256), 0, stream>>>(q_b, k_b, v_b, at_b);

  gemm_bt<float><<<dim3(32, 16, 1), dim3(256), 0, stream>>>(
      at_b, wo_b, out, 0L, 0L, 4096);
}